// Round 8
// baseline (1361.101 us; speedup 1.0000x reference)
//
#include <hip/hip_runtime.h>
#include <hip/hip_fp16.h>
#include <math.h>

#define TOK 2048      // B*S
#define HD 2048       // hidden
#define VOC 32000
#define BM 256
#define BN 256
#define BK 64
#define NT (HD/BK)                // 32 K-tiles
#define NCH (VOC/64)              // 500 col-chunks of 64
#define NBLK ((TOK/BM)*(VOC/BN))  // 8*125 = 1000

typedef _Float16 half8 __attribute__((ext_vector_type(8)));
typedef _Float16 half2v __attribute__((ext_vector_type(2)));
typedef __fp16   fp16x2 __attribute__((ext_vector_type(2)));
typedef float float4v __attribute__((ext_vector_type(4)));

#define GLB __attribute__((address_space(1)))
#define LDSAS __attribute__((address_space(3)))

static __device__ __forceinline__ void gload_lds16(const void* g, void* l) {
  __builtin_amdgcn_global_load_lds((const GLB unsigned int*)g,
                                   (LDSAS unsigned int*)l, 16, 0, 0);
}

static __device__ __forceinline__ float4v mfma16(half8 a, half8 b, float4v c) {
  return __builtin_amdgcn_mfma_f32_16x16x32_f16(a, b, c, 0, 0, 0);
}

// two float4 (8 fp32) -> half8 via v_cvt_pkrtz (RTZ; bias ~2^-12, negligible)
static __device__ __forceinline__ half8 cvt8(float4v a, float4v b) {
  half2v p0 = __builtin_bit_cast(half2v, __builtin_amdgcn_cvt_pkrtz(a[0], a[1]));
  half2v p1 = __builtin_bit_cast(half2v, __builtin_amdgcn_cvt_pkrtz(a[2], a[3]));
  half2v p2 = __builtin_bit_cast(half2v, __builtin_amdgcn_cvt_pkrtz(b[0], b[1]));
  half2v p3 = __builtin_bit_cast(half2v, __builtin_amdgcn_cvt_pkrtz(b[2], b[3]));
  half8 h;
  h[0]=p0[0]; h[1]=p0[1]; h[2]=p1[0]; h[3]=p1[1];
  h[4]=p2[0]; h[5]=p2[1]; h[6]=p3[0]; h[7]=p3[1];
  return h;
}

// ---------- fp32 -> f16 convert (X only; 8 MB, ~4 us) ----------
__global__ void cvt_f32_f16(const float* __restrict__ in,
                            _Float16* __restrict__ out, int n8) {
  for (int i = blockIdx.x * blockDim.x + threadIdx.x; i < n8;
       i += gridDim.x * blockDim.x) {
    float4v a = *(const float4v*)(in + (size_t)i*8);
    float4v b = *(const float4v*)(in + (size_t)i*8 + 4);
    half8 h;
    #pragma unroll
    for (int j=0;j<4;j++) { h[j] = (_Float16)a[j]; h[4+j] = (_Float16)b[j]; }
    *(half8*)(out + (size_t)i*8) = h;
  }
}

// A (X,f16) staged via global_load_lds, double-buffered 2x2 units of 16KB
// (64KB LDS). B (W,fp32) never touches LDS: per-wave fragment loads straight
// from global (L1/L2-shared across the 2 waves per wc; XCD swizzle keeps the
// col-tile's W panel in its XCD L2), cvt_pkrtz in-reg, one-phase prefetch in
// a single 32-VGPR set. Deadlines: each phase's cvt waits (compiler vmcnt) on
// last phase's B-refill, which is OLDER than every in-flight A-gload => A
// prefetch always landed before the barrier that publishes it.
template<int CB, bool SGA1, bool SGA2, bool SGB2>
__device__ __forceinline__ void ktile(
    unsigned char* ldsby, const char* Xb,
    const char* const (&wb)[4], int koffA,
    int sA0, int sA1, int ldst0, int ldst1, int kbn,
    const int (&aofs)[8], float4v (&bstg)[4][2], float4v (&acc)[8][4])
{
  half8 af[8], bf[4];

  // ================= Phase A: kk0 =================
  if (SGA1) {  // stage A(t+1,kk1) -> other buf, slot1
    gload_lds16(Xb + (sA0 + kbn + 64), ldsby + ((CB^32768) + 16384) + ldst0);
    gload_lds16(Xb + (sA1 + kbn + 64), ldsby + ((CB^32768) + 16384) + ldst1);
  }
  #pragma unroll
  for (int m=0;m<8;m++) af[m] = *(const half8*)(ldsby + CB + aofs[m]);
  #pragma unroll
  for (int n=0;n<4;n++) bf[n] = cvt8(bstg[n][0], bstg[n][1]);   // B(t,kk0)
  #pragma unroll
  for (int n=0;n<4;n++) {                                        // B(t,kk1)
    bstg[n][0] = *(const float4v*)(wb[n] + koffA);
    bstg[n][1] = *(const float4v*)(wb[n] + koffA + 16);
  }
  __builtin_amdgcn_s_setprio(1);
  #pragma unroll
  for (int m=0;m<8;m++)
    #pragma unroll
    for (int n=0;n<4;n++)
      acc[m][n] = mfma16(af[m], bf[n], acc[m][n]);
  __builtin_amdgcn_s_setprio(0);
  __builtin_amdgcn_s_barrier();

  // ================= Phase B: kk1 =================
  if (SGA2) {  // stage A(t+2,kk0) -> current buf, slot0
    gload_lds16(Xb + (sA0 + kbn + 128), ldsby + CB + ldst0);
    gload_lds16(Xb + (sA1 + kbn + 128), ldsby + CB + ldst1);
  }
  #pragma unroll
  for (int m=0;m<8;m++) af[m] = *(const half8*)(ldsby + CB + 16384 + aofs[m]);
  #pragma unroll
  for (int n=0;n<4;n++) bf[n] = cvt8(bstg[n][0], bstg[n][1]);   // B(t,kk1)
  if (SGB2) {
    #pragma unroll
    for (int n=0;n<4;n++) {                                      // B(t+1,kk0)
      bstg[n][0] = *(const float4v*)(wb[n] + koffA + 128);
      bstg[n][1] = *(const float4v*)(wb[n] + koffA + 144);
    }
  }
  __builtin_amdgcn_s_setprio(1);
  #pragma unroll
  for (int m=0;m<8;m++)
    #pragma unroll
    for (int n=0;n<4;n++)
      acc[m][n] = mfma16(af[m], bf[n], acc[m][n]);
  __builtin_amdgcn_s_setprio(0);
  __builtin_amdgcn_s_barrier();
}

// ---------- 256x256 GEMM, fused row stats; A via LDS, B reg-direct ----------
__global__ __launch_bounds__(512, 2) void gemm_stats_f16(
    const _Float16* __restrict__ Xh, const float* __restrict__ W32,
    const float* __restrict__ bias,
    float* __restrict__ pmax, float* __restrict__ psum,
    float* __restrict__ bsum, int computeSum)
{
  __shared__ unsigned char ldsbuf[65536];
  unsigned char* ldsby = ldsbuf;

  int bid = blockIdx.x;
  int swz = (bid & 7) * (NBLK/8) + (bid >> 3);   // XCD-aware, bijective (1000%8==0)
  int rowt = swz & 7;          // fast axis: 8 row tiles share W panel in XCD L2
  int colt = swz >> 3;         // 125 col tiles
  int brow = rowt * BM;
  int bcol = colt * BN;

  int tid  = threadIdx.x;
  int lane = tid & 63;
  int wv   = tid >> 6;
  int wr   = wv >> 2;          // 0..1 (M)
  int wc   = wv & 3;           // 0..3 (N)
  int l15  = lane & 15;
  int q    = lane >> 4;

  // A-fragment offsets within a 16KB unit (R6 pair-interleave, 0 conflicts)
  int aswz = (((((l15 & 1) << 2) | q) ^ ((l15 >> 1) & 7)) << 4) + ((l15 >> 1) << 7);
  int aofs[8];
  #pragma unroll
  for (int m = 0; m < 8; m++) aofs[m] = wr*8192 + m*1024 + aswz;

  // A staging: linear LDS dest, inverse-permuted global source (R6-verified)
  int s8  = (tid & 7) ^ ((tid >> 3) & 7);
  int rl  = wv*16 + (((tid >> 3) & 7) << 1) + (s8 >> 2);
  int kc  = (s8 & 3) << 4;
  int sA0 = (brow + rl)*(HD*2) + kc;
  int sA1 = sA0 + 128*(HD*2);
  int ldst0 = (wv << 10);          // wave-uniform LDS dest (+lane*16 by HW)
  int ldst1 = (wv << 10) + 8192;

  const char* Xb = (const char*)Xh;

  // B per-lane fp32 base pointers: row v = bcol + wc*64 + n*16 + l15, +q*32B
  const char* wb[4];
  {
    const char* Wc = (const char*)W32;
    int v0 = bcol + wc*64 + l15;
    #pragma unroll
    for (int n=0;n<4;n++)
      wb[n] = Wc + (size_t)(v0 + n*16) * (HD*4) + q*32;
  }

  float4v acc[8][4];
  #pragma unroll
  for (int m=0;m<8;m++)
    #pragma unroll
    for (int n=0;n<4;n++) acc[m][n] = (float4v){0.f,0.f,0.f,0.f};

  float4v bstg[4][2];

  // prologue: B(0,kk0) into regs; A(0,kk0),(0,kk1),(1,kk0) into LDS
  #pragma unroll
  for (int n=0;n<4;n++) {
    bstg[n][0] = *(const float4v*)(wb[n] + 0);
    bstg[n][1] = *(const float4v*)(wb[n] + 16);
  }
  gload_lds16(Xb + sA0,       ldsby + 0     + ldst0);
  gload_lds16(Xb + sA1,       ldsby + 0     + ldst1);
  gload_lds16(Xb + (sA0+64),  ldsby + 16384 + ldst0);
  gload_lds16(Xb + (sA1+64),  ldsby + 16384 + ldst1);
  gload_lds16(Xb + (sA0+128), ldsby + 32768 + ldst0);
  gload_lds16(Xb + (sA1+128), ldsby + 32768 + ldst1);
  asm volatile("s_waitcnt vmcnt(0)" ::: "memory");
  __builtin_amdgcn_s_barrier();

  int kbn   = 128;   // byte k-offset of tile t+1 (A source, f16)
  int koffA = 128;   // byte k-offset of B(t,kk1) (fp32: t*256+128)
  #pragma unroll 1
  for (int i = 0; i < 15; ++i) {
    ktile<0,     true, true, true>(ldsby, Xb, wb, koffA, sA0,sA1, ldst0,ldst1, kbn, aofs, bstg, acc);
    kbn += 128; koffA += 256;
    ktile<32768, true, true, true>(ldsby, Xb, wb, koffA, sA0,sA1, ldst0,ldst1, kbn, aofs, bstg, acc);
    kbn += 128; koffA += 256;
  }
  // t=30: A(31,kk1) yes, A(32,*) no, B(31,kk0) yes
  ktile<0,     true,  false, true >(ldsby, Xb, wb, koffA, sA0,sA1, ldst0,ldst1, kbn, aofs, bstg, acc);
  kbn += 128; koffA += 256;
  // t=31: no more staging
  ktile<32768, false, false, false>(ldsby, Xb, wb, koffA, sA0,sA1, ldst0,ldst1, kbn, aofs, bstg, acc);

  // ---------------- epilogue: bias + per-row max/sumexp ----------------
  float bv[4];
  #pragma unroll
  for (int n=0;n<4;n++) bv[n] = bias[bcol + wc*64 + n*16 + l15];

  float lsum = 0.f;
  int ch = colt*4 + wc;
  #pragma unroll
  for (int m=0;m<8;m++) {
    #pragma unroll
    for (int r=0;r<4;r++) {
      float v0 = acc[m][0][r] + bv[0];
      float v1 = acc[m][1][r] + bv[1];
      float v2 = acc[m][2][r] + bv[2];
      float v3 = acc[m][3][r] + bv[3];
      if (computeSum) lsum += v0+v1+v2+v3;
      float mx = fmaxf(fmaxf(v0,v1), fmaxf(v2,v3));
      #pragma unroll
      for (int off=1; off<16; off<<=1) mx = fmaxf(mx, __shfl_xor(mx, off, 64));
      float se = __expf(v0-mx)+__expf(v1-mx)+__expf(v2-mx)+__expf(v3-mx);
      #pragma unroll
      for (int off=1; off<16; off<<=1) se += __shfl_xor(se, off, 64);
      if (l15 == 0) {
        int row = brow + wr*128 + m*16 + (lane>>4)*4 + r;
        pmax[(size_t)row*NCH + ch] = mx;
        psum[(size_t)row*NCH + ch] = se;
      }
    }
  }

  if (computeSum) {
    #pragma unroll
    for (int off=1; off<64; off<<=1) lsum += __shfl_xor(lsum, off, 64);
    __syncthreads();
    float* red = (float*)ldsbuf;
    if (lane == 0) red[wv] = lsum;
    __syncthreads();
    if (tid == 0) {
      float s = 0.f;
      for (int w=0; w<8; w++) s += red[w];
      bsum[blockIdx.x] = s;
    }
  }
}

// ---------- per-row combine ----------
__global__ void row_combine(const float* __restrict__ pmax,
                            const float* __restrict__ psum,
                            const float* __restrict__ mask,
                            float* __restrict__ tok)
{
  int row = blockIdx.x;
  int lane = threadIdx.x;
  float M = -INFINITY;
  for (int c = lane; c < NCH; c += 64) M = fmaxf(M, pmax[(size_t)row*NCH + c]);
  #pragma unroll
  for (int off=1; off<64; off<<=1) M = fmaxf(M, __shfl_xor(M, off, 64));
  float L = 0.f;
  for (int c = lane; c < NCH; c += 64)
    L += psum[(size_t)row*NCH + c] * __expf(pmax[(size_t)row*NCH + c] - M);
  #pragma unroll
  for (int off=1; off<64; off<<=1) L += __shfl_xor(L, off, 64);
  if (lane == 0) tok[row] = -logf(L) * mask[row];
}

// ---------- finalize ----------
__global__ void finalize(const float* __restrict__ tokP,
                         const float* __restrict__ tokR,
                         const float* __restrict__ rewards,
                         const float* __restrict__ bsum, int nbsum,
                         float* __restrict__ out)
{
  __shared__ float red[256];
  __shared__ float seqP[4], seqR[4];
  int t = threadIdx.x;
  for (int b=0; b<4; b++) {
    float v = tokP[b*512 + t] + tokP[b*512 + 256 + t];
    red[t] = v; __syncthreads();
    for (int s=128; s>0; s>>=1) { if (t < s) red[t] += red[t+s]; __syncthreads(); }
    if (t == 0) seqP[b] = red[0];
    __syncthreads();
    v = tokR[b*512 + t] + tokR[b*512 + 256 + t];
    red[t] = v; __syncthreads();
    for (int s=128; s>0; s>>=1) { if (t < s) red[t] += red[t+s]; __syncthreads(); }
    if (t == 0) seqR[b] = red[0];
    __syncthreads();
  }
  float ls = 0.f;
  for (int i=t; i<nbsum; i+=256) ls += bsum[i];
  red[t] = ls; __syncthreads();
  for (int s=128; s>0; s>>=1) { if (t < s) red[t] += red[t+s]; __syncthreads(); }
  if (t == 0) {
    float r0=rewards[0], r1=rewards[1], r2=rewards[2], r3=rewards[3];
    float rm = (r0+r1+r2+r3)*0.25f;
    float var = ((r0-rm)*(r0-rm)+(r1-rm)*(r1-rm)+(r2-rm)*(r2-rm)+(r3-rm)*(r3-rm))/3.f;
    float rstd = sqrtf(var);
    float adv[4] = {r0-rm, r1-rm, r2-rm, r3-rm};
    if (rstd > 0.f) { for (int b=0;b<4;b++) adv[b] /= rstd; }
    float loss=0.f, sm=0.f, km=0.f;
    for (int b=0;b<4;b++) {
      float kl = seqP[b] - seqR[b];
      loss += -(adv[b]*seqP[b]) + 0.1f*kl;
      sm += seqP[b]; km += kl;
    }
    loss *= 0.25f; sm *= 0.25f; km *= 0.25f;
    float sv = 0.f;
    for (int b=0;b<4;b++) { float d = seqP[b]-sm; sv += d*d; }
    float sstd = sqrtf(sv/3.f);
    out[0] = loss;
    out[1] = sm;
    out[2] = sstd;
    out[3] = red[0] / ((float)TOK * (float)VOC);
    out[4] = km;
  }
}

extern "C" void kernel_launch(void* const* d_in, const int* in_sizes, int n_in,
                              void* d_out, int out_size, void* d_ws, size_t ws_size,
                              hipStream_t stream) {
  const float* W    = (const float*)d_in[0];
  const float* X    = (const float*)d_in[1];
  const float* mask = (const float*)d_in[2];
  const float* rew  = (const float*)d_in[3];
  const float* bias = (const float*)d_in[4];
  const float* Xr   = (const float*)d_in[5];
  const float* Wr   = (const float*)d_in[6];
  const float* br   = (const float*)d_in[7];
  float* out = (float*)d_out;

  float* pmax = (float*)d_ws;                       // 2048*500
  float* psum = pmax + (size_t)TOK*NCH;             // 2048*500
  float* tokP = psum + (size_t)TOK*NCH;             // 2048
  float* tokR = tokP + TOK;                         // 2048
  float* bsum = tokR + TOK;                         // 4096 (pad)

  size_t headFloats = (size_t)TOK*NCH*2 + TOK*2 + 4096;
  size_t offXh = headFloats * 4;
  _Float16* Xh = (_Float16*)((unsigned char*)d_ws + offXh);

  cvt_f32_f16<<<2048, 256, 0, stream>>>(X,  Xh, TOK*HD/8);
  gemm_stats_f16<<<NBLK, 512, 0, stream>>>(Xh, W, bias, pmax, psum, bsum, 1);
  row_combine<<<TOK, 64, 0, stream>>>(pmax, psum, mask, tokP);
  cvt_f32_f16<<<2048, 256, 0, stream>>>(Xr, Xh, TOK*HD/8);
  gemm_stats_f16<<<NBLK, 512, 0, stream>>>(Xh, Wr, br, pmax, psum, bsum, 0);
  row_combine<<<TOK, 64, 0, stream>>>(pmax, psum, mask, tokR);
  finalize<<<1, 256, 0, stream>>>(tokP, tokR, rew, bsum, NBLK, out);
}

// Round 9
// 688.262 us; speedup vs baseline: 1.9776x; 1.9776x over previous
//
#include <hip/hip_runtime.h>
#include <hip/hip_fp16.h>
#include <math.h>

#define TOK 2048      // B*S
#define HD 2048       // hidden
#define VOC 32000
#define BM 256
#define BN 256
#define BK 64
#define NT (HD/BK)                // 32 K-tiles
#define NCH (VOC/64)              // 500 col-chunks of 64
#define NBLK ((TOK/BM)*(VOC/BN))  // 8*125 = 1000

typedef _Float16 half8 __attribute__((ext_vector_type(8)));
typedef _Float16 half2v __attribute__((ext_vector_type(2)));
typedef float float4v __attribute__((ext_vector_type(4)));

#define GLB __attribute__((address_space(1)))
#define LDSAS __attribute__((address_space(3)))

static __device__ __forceinline__ void gload_lds16(const void* g, void* l) {
  __builtin_amdgcn_global_load_lds((const GLB unsigned int*)g,
                                   (LDSAS unsigned int*)l, 16, 0, 0);
}

static __device__ __forceinline__ float4v mfma16(half8 a, half8 b, float4v c) {
  return __builtin_amdgcn_mfma_f32_16x16x32_f16(a, b, c, 0, 0, 0);
}

// 8 fp32 -> half8 via v_cvt_pkrtz (RTZ; rel err ~2^-12, negligible here)
static __device__ __forceinline__ half8 cvt8(float4v a, float4v b) {
  half2v p0 = __builtin_bit_cast(half2v, __builtin_amdgcn_cvt_pkrtz(a[0], a[1]));
  half2v p1 = __builtin_bit_cast(half2v, __builtin_amdgcn_cvt_pkrtz(a[2], a[3]));
  half2v p2 = __builtin_bit_cast(half2v, __builtin_amdgcn_cvt_pkrtz(b[0], b[1]));
  half2v p3 = __builtin_bit_cast(half2v, __builtin_amdgcn_cvt_pkrtz(b[2], b[3]));
  half8 h;
  h[0]=p0[0]; h[1]=p0[1]; h[2]=p1[0]; h[3]=p1[1];
  h[4]=p2[0]; h[5]=p2[1]; h[6]=p3[0]; h[7]=p3[1];
  return h;
}

// ---------- fp32 -> f16 convert (X only; 8 MB, ~4 us) ----------
__global__ void cvt_f32_f16(const float* __restrict__ in,
                            _Float16* __restrict__ out, int n8) {
  for (int i = blockIdx.x * blockDim.x + threadIdx.x; i < n8;
       i += gridDim.x * blockDim.x) {
    float4v a = *(const float4v*)(in + (size_t)i*8);
    float4v b = *(const float4v*)(in + (size_t)i*8 + 4);
    half8 h;
    #pragma unroll
    for (int j=0;j<4;j++) { h[j] = (_Float16)a[j]; h[4+j] = (_Float16)b[j]; }
    *(half8*)(out + (size_t)i*8) = h;
  }
}

// LDS map (128KB): A f16 dbuf: buf0 kk0 @0, kk1 @16K; buf1 @32K,48K (R6 layout).
// B fp32 single-buffered per kk: Bk0 @64K (32KB), Bk1 @96K (32KB).
// B unit: 256 rows x 128B (32 fp32); byte = row*128 + ((slot ^ (row&7))<<4).
// Staged linear-dest; inverse perm folded into global source (rule #21).
// Per tile: phase A {read A(t,kk0)+Bk0; lgkm0; midA barrier; stage A(t+1,kk1),
// B(t+1,kk0); cvt; 32 MFMA; vmcnt(6); endA barrier}; phase B symmetric with
// stages A(t+2,kk0), B(t+1,kk1). vmcnt(6) = own phase's 6 loads in flight =>
// everything older landed. Hazards: each stage's target region last read
// before >=1 barrier (midA/midB protect same-phase B re-stage; A regions 2+
// barriers). Tail: endB(t=30) vmcnt(4) so B(31,kk0) lands; endA(31) vmcnt(0).
template<int CB, bool SGA1, bool SGB1, bool SGA2, bool SGB2, int VM1, int VM2>
__device__ __forceinline__ void ktile(
    unsigned char* ldsby, const char* Xb, const char* Wb,
    int sA0, int sA1, int sB, int ldst0, int ldst1, int ldstB,
    int kbnA, int kbnB,
    const int (&aofs)[8], const int (&bof)[4][2], float4v (&acc)[8][4])
{
  half8 af[8], bf[4];
  float4v bw[8];

  // ================= Phase A: kk0 =================
  #pragma unroll
  for (int m=0;m<8;m++) af[m] = *(const half8*)(ldsby + CB + aofs[m]);
  #pragma unroll
  for (int n=0;n<4;n++) {
    bw[2*n]   = *(const float4v*)(ldsby + 65536 + bof[n][0]);
    bw[2*n+1] = *(const float4v*)(ldsby + 65536 + bof[n][1]);
  }
  asm volatile("s_waitcnt lgkmcnt(0)" ::: "memory");
  __builtin_amdgcn_sched_barrier(0);
  __builtin_amdgcn_s_barrier();                    // midA: Bk0 reads published
  if (SGA1) {  // A(t+1,kk1) -> other buf slot1
    gload_lds16(Xb + (sA0 + kbnA + 64), ldsby + ((CB^32768) + 16384) + ldst0);
    gload_lds16(Xb + (sA1 + kbnA + 64), ldsby + ((CB^32768) + 16384) + ldst1);
  }
  if (SGB1) {  // B(t+1,kk0) -> Bk0
    #pragma unroll
    for (int i=0;i<4;i++)
      gload_lds16(Wb + (sB + kbnB + i*(64*HD*4)), ldsby + 65536 + i*8192 + ldstB);
  }
  #pragma unroll
  for (int n=0;n<4;n++) bf[n] = cvt8(bw[2*n], bw[2*n+1]);
  __builtin_amdgcn_s_setprio(1);
  #pragma unroll
  for (int m=0;m<8;m++)
    #pragma unroll
    for (int n=0;n<4;n++)
      acc[m][n] = mfma16(af[m], bf[n], acc[m][n]);
  __builtin_amdgcn_s_setprio(0);
  if (VM1==6)      asm volatile("s_waitcnt vmcnt(6)" ::: "memory");
  else if (VM1==4) asm volatile("s_waitcnt vmcnt(4)" ::: "memory");
  else if (VM1==0) asm volatile("s_waitcnt vmcnt(0)" ::: "memory");
  __builtin_amdgcn_s_barrier();                    // endA

  // ================= Phase B: kk1 =================
  #pragma unroll
  for (int m=0;m<8;m++) af[m] = *(const half8*)(ldsby + CB + 16384 + aofs[m]);
  #pragma unroll
  for (int n=0;n<4;n++) {
    bw[2*n]   = *(const float4v*)(ldsby + 98304 + bof[n][0]);
    bw[2*n+1] = *(const float4v*)(ldsby + 98304 + bof[n][1]);
  }
  asm volatile("s_waitcnt lgkmcnt(0)" ::: "memory");
  __builtin_amdgcn_sched_barrier(0);
  __builtin_amdgcn_s_barrier();                    // midB: Bk1 reads published
  if (SGA2) {  // A(t+2,kk0) -> current buf slot0
    gload_lds16(Xb + (sA0 + kbnA + 128), ldsby + CB + ldst0);
    gload_lds16(Xb + (sA1 + kbnA + 128), ldsby + CB + ldst1);
  }
  if (SGB2) {  // B(t+1,kk1) -> Bk1
    #pragma unroll
    for (int i=0;i<4;i++)
      gload_lds16(Wb + (sB + kbnB + 128 + i*(64*HD*4)), ldsby + 98304 + i*8192 + ldstB);
  }
  #pragma unroll
  for (int n=0;n<4;n++) bf[n] = cvt8(bw[2*n], bw[2*n+1]);
  __builtin_amdgcn_s_setprio(1);
  #pragma unroll
  for (int m=0;m<8;m++)
    #pragma unroll
    for (int n=0;n<4;n++)
      acc[m][n] = mfma16(af[m], bf[n], acc[m][n]);
  __builtin_amdgcn_s_setprio(0);
  if (VM2==6)      asm volatile("s_waitcnt vmcnt(6)" ::: "memory");
  else if (VM2==4) asm volatile("s_waitcnt vmcnt(4)" ::: "memory");
  else if (VM2==0) asm volatile("s_waitcnt vmcnt(0)" ::: "memory");
  __builtin_amdgcn_s_barrier();                    // endB
}

// ---------- 256x256 GEMM, fused row stats; A f16 LDS, B fp32 LDS ----------
__global__ __launch_bounds__(512, 2) void gemm_stats_f16(
    const _Float16* __restrict__ Xh, const float* __restrict__ W32,
    const float* __restrict__ bias,
    float* __restrict__ pmax, float* __restrict__ psum,
    float* __restrict__ bsum, int computeSum)
{
  __shared__ unsigned char ldsbuf[131072];
  unsigned char* ldsby = ldsbuf;

  int bid = blockIdx.x;
  int swz = (bid & 7) * (NBLK/8) + (bid >> 3);   // XCD-aware, bijective (1000%8==0)
  int rowt = swz & 7;          // fast axis: 8 row tiles share W panel in XCD L2
  int colt = swz >> 3;         // 125 col tiles
  int brow = rowt * BM;
  int bcol = colt * BN;

  int tid  = threadIdx.x;
  int lane = tid & 63;
  int wv   = tid >> 6;
  int wr   = wv >> 2;          // 0..1 (M)
  int wc   = wv & 3;           // 0..3 (N)
  int l15  = lane & 15;
  int q    = lane >> 4;

  // A-fragment offsets within a 16KB unit (R6 pair-interleave, 0 conflicts)
  int aswz = (((((l15 & 1) << 2) | q) ^ ((l15 >> 1) & 7)) << 4) + ((l15 >> 1) << 7);
  int aofs[8];
  #pragma unroll
  for (int m = 0; m < 8; m++) aofs[m] = wr*8192 + m*1024 + aswz;

  // B-fragment offsets within a 32KB fp32 unit: row*128 ^ slot-swizzle
  int bof[4][2];
  #pragma unroll
  for (int n = 0; n < 4; n++) {
    int r = wc*64 + n*16 + l15;
    int x = r & 7;
    bof[n][0] = r*128 + (((2*q)   ^ x) << 4);
    bof[n][1] = r*128 + (((2*q+1) ^ x) << 4);
  }

  // A staging: linear LDS dest, inverse-permuted global source (R6-verified)
  int s8  = (tid & 7) ^ ((tid >> 3) & 7);
  int rl  = wv*16 + (((tid >> 3) & 7) << 1) + (s8 >> 2);
  int kc  = (s8 & 3) << 4;
  int sA0 = (brow + rl)*(HD*2) + kc;
  int sA1 = sA0 + 128*(HD*2);
  int ldst0 = (wv << 10);          // wave-uniform LDS dest (+lane*16 by HW)
  int ldst1 = (wv << 10) + 8192;

  // B staging: thread -> (row = tid>>3, physslot = tid&7); logical slot =
  // physslot ^ (row&7); source = W32[(bcol+row)*HD*4 + kk + slot*16]
  int sB = (bcol + (tid >> 3))*(HD*4) + (((tid & 7) ^ ((tid >> 3) & 7)) << 4);
  int ldstB = (wv << 10);

  const char* Xb = (const char*)Xh;
  const char* Wb = (const char*)W32;

  float4v acc[8][4];
  #pragma unroll
  for (int m=0;m<8;m++)
    #pragma unroll
    for (int n=0;n<4;n++) acc[m][n] = (float4v){0.f,0.f,0.f,0.f};

  // prologue: A(0,kk0)@0 A(0,kk1)@16K A(1,kk0)@32K; B(0,kk0)@64K B(0,kk1)@96K
  gload_lds16(Xb + sA0,       ldsby + 0     + ldst0);
  gload_lds16(Xb + sA1,       ldsby + 0     + ldst1);
  gload_lds16(Xb + (sA0+64),  ldsby + 16384 + ldst0);
  gload_lds16(Xb + (sA1+64),  ldsby + 16384 + ldst1);
  gload_lds16(Xb + (sA0+128), ldsby + 32768 + ldst0);
  gload_lds16(Xb + (sA1+128), ldsby + 32768 + ldst1);
  #pragma unroll
  for (int i=0;i<4;i++)
    gload_lds16(Wb + (sB + i*(64*HD*4)),       ldsby + 65536 + i*8192 + ldstB);
  #pragma unroll
  for (int i=0;i<4;i++)
    gload_lds16(Wb + (sB + 128 + i*(64*HD*4)), ldsby + 98304 + i*8192 + ldstB);
  asm volatile("s_waitcnt vmcnt(0)" ::: "memory");
  __builtin_amdgcn_s_barrier();

  int kbnA = 128;   // f16 byte k-offset of tile t+1
  int kbnB = 256;   // fp32 byte k-offset of tile t+1
  #pragma unroll 1
  for (int i = 0; i < 15; ++i) {
    ktile<0,     true,true,true,true, 6,6>(ldsby, Xb, Wb, sA0,sA1,sB, ldst0,ldst1,ldstB, kbnA,kbnB, aofs, bof, acc);
    kbnA += 128; kbnB += 256;
    ktile<32768, true,true,true,true, 6,6>(ldsby, Xb, Wb, sA0,sA1,sB, ldst0,ldst1,ldstB, kbnA,kbnB, aofs, bof, acc);
    kbnA += 128; kbnB += 256;
  }
  // t=30: stage A(31,kk1), B(31,kk0), B(31,kk1); no A(32); endB waits vmcnt(4)
  ktile<0,     true,true,false,true, 6,4>(ldsby, Xb, Wb, sA0,sA1,sB, ldst0,ldst1,ldstB, kbnA,kbnB, aofs, bof, acc);
  kbnA += 128; kbnB += 256;
  // t=31: no staging; endA drains
  ktile<32768, false,false,false,false, 0,-1>(ldsby, Xb, Wb, sA0,sA1,sB, ldst0,ldst1,ldstB, kbnA,kbnB, aofs, bof, acc);

  // ---------------- epilogue: bias + per-row max/sumexp ----------------
  float bv[4];
  #pragma unroll
  for (int n=0;n<4;n++) bv[n] = bias[bcol + wc*64 + n*16 + l15];

  float lsum = 0.f;
  int ch = colt*4 + wc;
  #pragma unroll
  for (int m=0;m<8;m++) {
    #pragma unroll
    for (int r=0;r<4;r++) {
      float v0 = acc[m][0][r] + bv[0];
      float v1 = acc[m][1][r] + bv[1];
      float v2 = acc[m][2][r] + bv[2];
      float v3 = acc[m][3][r] + bv[3];
      if (computeSum) lsum += v0+v1+v2+v3;
      float mx = fmaxf(fmaxf(v0,v1), fmaxf(v2,v3));
      #pragma unroll
      for (int off=1; off<16; off<<=1) mx = fmaxf(mx, __shfl_xor(mx, off, 64));
      float se = __expf(v0-mx)+__expf(v1-mx)+__expf(v2-mx)+__expf(v3-mx);
      #pragma unroll
      for (int off=1; off<16; off<<=1) se += __shfl_xor(se, off, 64);
      if (l15 == 0) {
        int row = brow + wr*128 + m*16 + (lane>>4)*4 + r;
        pmax[(size_t)row*NCH + ch] = mx;
        psum[(size_t)row*NCH + ch] = se;
      }
    }
  }

  if (computeSum) {
    #pragma unroll
    for (int off=1; off<64; off<<=1) lsum += __shfl_xor(lsum, off, 64);
    __syncthreads();
    float* red = (float*)ldsbuf;
    if (lane == 0) red[wv] = lsum;
    __syncthreads();
    if (tid == 0) {
      float s = 0.f;
      for (int w=0; w<8; w++) s += red[w];
      bsum[blockIdx.x] = s;
    }
  }
}

// ---------- per-row combine ----------
__global__ void row_combine(const float* __restrict__ pmax,
                            const float* __restrict__ psum,
                            const float* __restrict__ mask,
                            float* __restrict__ tok)
{
  int row = blockIdx.x;
  int lane = threadIdx.x;
  float M = -INFINITY;
  for (int c = lane; c < NCH; c += 64) M = fmaxf(M, pmax[(size_t)row*NCH + c]);
  #pragma unroll
  for (int off=1; off<64; off<<=1) M = fmaxf(M, __shfl_xor(M, off, 64));
  float L = 0.f;
  for (int c = lane; c < NCH; c += 64)
    L += psum[(size_t)row*NCH + c] * __expf(pmax[(size_t)row*NCH + c] - M);
  #pragma unroll
  for (int off=1; off<64; off<<=1) L += __shfl_xor(L, off, 64);
  if (lane == 0) tok[row] = -logf(L) * mask[row];
}

// ---------- finalize ----------
__global__ void finalize(const float* __restrict__ tokP,
                         const float* __restrict__ tokR,
                         const float* __restrict__ rewards,
                         const float* __restrict__ bsum, int nbsum,
                         float* __restrict__ out)
{
  __shared__ float red[256];
  __shared__ float seqP[4], seqR[4];
  int t = threadIdx.x;
  for (int b=0; b<4; b++) {
    float v = tokP[b*512 + t] + tokP[b*512 + 256 + t];
    red[t] = v; __syncthreads();
    for (int s=128; s>0; s>>=1) { if (t < s) red[t] += red[t+s]; __syncthreads(); }
    if (t == 0) seqP[b] = red[0];
    __syncthreads();
    v = tokR[b*512 + t] + tokR[b*512 + 256 + t];
    red[t] = v; __syncthreads();
    for (int s=128; s>0; s>>=1) { if (t < s) red[t] += red[t+s]; __syncthreads(); }
    if (t == 0) seqR[b] = red[0];
    __syncthreads();
  }
  float ls = 0.f;
  for (int i=t; i<nbsum; i+=256) ls += bsum[i];
  red[t] = ls; __syncthreads();
  for (int s=128; s>0; s>>=1) { if (t < s) red[t] += red[t+s]; __syncthreads(); }
  if (t == 0) {
    float r0=rewards[0], r1=rewards[1], r2=rewards[2], r3=rewards[3];
    float rm = (r0+r1+r2+r3)*0.25f;
    float var = ((r0-rm)*(r0-rm)+(r1-rm)*(r1-rm)+(r2-rm)*(r2-rm)+(r3-rm)*(r3-rm))/3.f;
    float rstd = sqrtf(var);
    float adv[4] = {r0-rm, r1-rm, r2-rm, r3-rm};
    if (rstd > 0.f) { for (int b=0;b<4;b++) adv[b] /= rstd; }
    float loss=0.f, sm=0.f, km=0.f;
    for (int b=0;b<4;b++) {
      float kl = seqP[b] - seqR[b];
      loss += -(adv[b]*seqP[b]) + 0.1f*kl;
      sm += seqP[b]; km += kl;
    }
    loss *= 0.25f; sm *= 0.25f; km *= 0.25f;
    float sv = 0.f;
    for (int b=0;b<4;b++) { float d = seqP[b]-sm; sv += d*d; }
    float sstd = sqrtf(sv/3.f);
    out[0] = loss;
    out[1] = sm;
    out[2] = sstd;
    out[3] = red[0] / ((float)TOK * (float)VOC);
    out[4] = km;
  }
}

extern "C" void kernel_launch(void* const* d_in, const int* in_sizes, int n_in,
                              void* d_out, int out_size, void* d_ws, size_t ws_size,
                              hipStream_t stream) {
  const float* W    = (const float*)d_in[0];
  const float* X    = (const float*)d_in[1];
  const float* mask = (const float*)d_in[2];
  const float* rew  = (const float*)d_in[3];
  const float* bias = (const float*)d_in[4];
  const float* Xr   = (const float*)d_in[5];
  const float* Wr   = (const float*)d_in[6];
  const float* br   = (const float*)d_in[7];
  float* out = (float*)d_out;

  float* pmax = (float*)d_ws;                       // 2048*500
  float* psum = pmax + (size_t)TOK*NCH;             // 2048*500
  float* tokP = psum + (size_t)TOK*NCH;             // 2048
  float* tokR = tokP + TOK;                         // 2048
  float* bsum = tokR + TOK;                         // 4096 (pad)

  size_t headFloats = (size_t)TOK*NCH*2 + TOK*2 + 4096;
  size_t offXh = headFloats * 4;
  _Float16* Xh = (_Float16*)((unsigned char*)d_ws + offXh);

  cvt_f32_f16<<<2048, 256, 0, stream>>>(X,  Xh, TOK*HD/8);
  gemm_stats_f16<<<NBLK, 512, 0, stream>>>(Xh, W, bias, pmax, psum, bsum, 1);
  row_combine<<<TOK, 64, 0, stream>>>(pmax, psum, mask, tokP);
  cvt_f32_f16<<<2048, 256, 0, stream>>>(Xr, Xh, TOK*HD/8);
  gemm_stats_f16<<<NBLK, 512, 0, stream>>>(Xh, Wr, br, pmax, psum, bsum, 0);
  row_combine<<<TOK, 64, 0, stream>>>(pmax, psum, mask, tokR);
  finalize<<<1, 256, 0, stream>>>(tokP, tokR, rew, bsum, NBLK, out);
}

// Round 10
// 679.524 us; speedup vs baseline: 2.0030x; 1.0129x over previous
//
#include <hip/hip_runtime.h>
#include <hip/hip_fp16.h>
#include <math.h>

#define TOK 2048      // B*S
#define HD 2048       // hidden
#define VOC 32000
#define BM 256
#define BN 256
#define BK 64
#define NT (HD/BK)                // 32 K-tiles
#define NCH (VOC/64)              // 500 col-chunks of 64
#define NBLK ((TOK/BM)*(VOC/BN))  // 8*125 = 1000

typedef _Float16 half8 __attribute__((ext_vector_type(8)));
typedef float float4v __attribute__((ext_vector_type(4)));

#define GLB __attribute__((address_space(1)))
#define LDSAS __attribute__((address_space(3)))

static __device__ __forceinline__ void gload_lds16(const void* g, void* l) {
  __builtin_amdgcn_global_load_lds((const GLB unsigned int*)g,
                                   (LDSAS unsigned int*)l, 16, 0, 0);
}

static __device__ __forceinline__ float4v mfma16(half8 a, half8 b, float4v c) {
  return __builtin_amdgcn_mfma_f32_16x16x32_f16(a, b, c, 0, 0, 0);
}

// ---------- fp32 -> f16 convert (memory-bound, vectorized) ----------
__global__ void cvt_f32_f16(const float* __restrict__ in,
                            _Float16* __restrict__ out, int n8) {
  for (int i = blockIdx.x * blockDim.x + threadIdx.x; i < n8;
       i += gridDim.x * blockDim.x) {
    float4v a = *(const float4v*)(in + (size_t)i*8);
    float4v b = *(const float4v*)(in + (size_t)i*8 + 4);
    half8 h;
    #pragma unroll
    for (int j=0;j<4;j++) { h[j] = (_Float16)a[j]; h[4+j] = (_Float16)b[j]; }
    *(half8*)(out + (size_t)i*8) = h;
  }
}

// R6 base (267us, 0 bank conflicts) + symmetric phase-ahead prefetch.
// Units (16KB): u0=A kk0 @CB, u1=B kk0 @CB+16K, u2=A kk1 @CB+32K, u3=B kk1
// @CB+48K; CB in {0,65536}. Pair-interleaved conflict-free layout (R6).
// Schedule per tile t (cur buf CB):
//  Phase A: hi-read u0.aofs[4..7]; stage (t+1)kk1 -> other.u2,u3 [4 gloads];
//    MFMA m0-3 (pfa,pfb from prev phase's prefetch); prefetch qb<-u3, qalo<-u2;
//    MFMA m4-7 (hi,pfb); vmcnt(4); barrier.
//  Phase B: hi-read u2.aofs[4..7]; stage (t+2)kk0 -> cur.u0,u1 [4 gloads];
//    MFMA m0-3 (qalo,qb); prefetch pfb<-other.u1, pfa<-other.u0 (next tile);
//    MFMA m4-7 (hi,qb); vmcnt(4); barrier.
// vmcnt(4) at EACH phase end: in flight = this phase's 4; all older landed =>
//  - endA(t): B(t-1)'s staged (t+1)kk0 landed -> phase B's pfa/pfb source OK.
//  - endB(t): A(t)'s staged (t+1)kk1 landed -> next phase-A's q source OK.
// Write-after-read: stage targets' last readers are >=1 barrier earlier
// (cur.u0/u1 read by A(t) hi + B(t-1) prefetch, both before endA(t);
//  other.u2/u3 read by A(t-1)'s q-prefetch, 2 barriers earlier).
// Tail: endB(30) vmcnt(0) so tile31 kk1 resident for A(31)'s q-prefetch.
template<int CB, bool SG1, bool SG2, bool PF, int VM1, int VM2>
__device__ __forceinline__ void ktile(
    unsigned char* ldsby, const char* Xb, const char* Wb,
    int sA0, int sA1, int sB0, int sB1,
    int ldst0, int ldst1, int kbn,
    const int (&aofs)[8], const int (&bofs)[4],
    half8 (&pfa)[4], half8 (&pfb)[4], float4v (&acc)[8][4])
{
  half8 hi[4], qalo[4], qb[4];

  // ================= Phase A: kk0 =================
  #pragma unroll
  for (int m=0;m<4;m++) hi[m] = *(const half8*)(ldsby + CB + aofs[4+m]);
  if (SG1) {   // stage (t+1) kk1: A -> other.u2, B -> other.u3
    gload_lds16(Xb + (sA0 + kbn + 64), ldsby + ((CB^65536) + 32768) + ldst0);
    gload_lds16(Xb + (sA1 + kbn + 64), ldsby + ((CB^65536) + 32768) + ldst1);
    gload_lds16(Wb + (sB0 + kbn + 64), ldsby + ((CB^65536) + 49152) + ldst0);
    gload_lds16(Wb + (sB1 + kbn + 64), ldsby + ((CB^65536) + 49152) + ldst1);
  }
  __builtin_amdgcn_s_setprio(1);
  #pragma unroll
  for (int m=0;m<4;m++)
    #pragma unroll
    for (int n=0;n<4;n++)
      acc[m][n] = mfma16(pfa[m], pfb[n], acc[m][n]);
  #pragma unroll
  for (int n=0;n<4;n++) qb[n]   = *(const half8*)(ldsby + CB + 49152 + bofs[n]);
  #pragma unroll
  for (int m=0;m<4;m++) qalo[m] = *(const half8*)(ldsby + CB + 32768 + aofs[m]);
  #pragma unroll
  for (int m=0;m<4;m++)
    #pragma unroll
    for (int n=0;n<4;n++)
      acc[4+m][n] = mfma16(hi[m], pfb[n], acc[4+m][n]);
  __builtin_amdgcn_s_setprio(0);
  if (VM1==4)      asm volatile("s_waitcnt vmcnt(4)" ::: "memory");
  else if (VM1==0) asm volatile("s_waitcnt vmcnt(0)" ::: "memory");
  __builtin_amdgcn_s_barrier();

  // ================= Phase B: kk1 =================
  #pragma unroll
  for (int m=0;m<4;m++) hi[m] = *(const half8*)(ldsby + CB + 32768 + aofs[4+m]);
  if (SG2) {   // stage (t+2) kk0: A -> cur.u0, B -> cur.u1
    gload_lds16(Xb + (sA0 + kbn + 128), ldsby + CB + ldst0);
    gload_lds16(Xb + (sA1 + kbn + 128), ldsby + CB + ldst1);
    gload_lds16(Wb + (sB0 + kbn + 128), ldsby + (CB + 16384) + ldst0);
    gload_lds16(Wb + (sB1 + kbn + 128), ldsby + (CB + 16384) + ldst1);
  }
  __builtin_amdgcn_s_setprio(1);
  #pragma unroll
  for (int m=0;m<4;m++)
    #pragma unroll
    for (int n=0;n<4;n++)
      acc[m][n] = mfma16(qalo[m], qb[n], acc[m][n]);
  if (PF) {    // prefetch next tile's phase-A lo set from other buf
    #pragma unroll
    for (int n=0;n<4;n++) pfb[n] = *(const half8*)(ldsby + (CB^65536) + 16384 + bofs[n]);
    #pragma unroll
    for (int m=0;m<4;m++) pfa[m] = *(const half8*)(ldsby + (CB^65536) + aofs[m]);
  }
  #pragma unroll
  for (int m=0;m<4;m++)
    #pragma unroll
    for (int n=0;n<4;n++)
      acc[4+m][n] = mfma16(hi[m], qb[n], acc[4+m][n]);
  __builtin_amdgcn_s_setprio(0);
  if (VM2==4)      asm volatile("s_waitcnt vmcnt(4)" ::: "memory");
  else if (VM2==0) asm volatile("s_waitcnt vmcnt(0)" ::: "memory");
  __builtin_amdgcn_s_barrier();
}

// ---------- 256x256 GEMM with fused row stats ----------
__global__ __launch_bounds__(512, 2) void gemm_stats_f16(
    const _Float16* __restrict__ Xh, const _Float16* __restrict__ Wh,
    const float* __restrict__ bias,
    float* __restrict__ pmax, float* __restrict__ psum,
    float* __restrict__ bsum, int computeSum)
{
  __shared__ unsigned char ldsbuf[131072];
  unsigned char* ldsby = ldsbuf;

  int bid = blockIdx.x;
  int swz = (bid & 7) * (NBLK/8) + (bid >> 3);   // XCD-aware, bijective (1000%8==0)
  int rowt = swz & 7;          // fast axis: 8 row tiles share W panel in XCD L2
  int colt = swz >> 3;         // 125 col tiles
  int brow = rowt * BM;
  int bcol = colt * BN;

  int tid  = threadIdx.x;
  int lane = tid & 63;
  int wv   = tid >> 6;
  int wr   = wv >> 2;          // 0..1 (M)
  int wc   = wv & 3;           // 0..3 (N)
  int l15  = lane & 15;
  int q    = lane >> 4;

  // fragment offsets within a 16KB unit (R6 pair-interleave, 0 conflicts)
  int aswz = (((((l15 & 1) << 2) | q) ^ ((l15 >> 1) & 7)) << 4) + ((l15 >> 1) << 7);
  int aofs[8], bofs[4];
  #pragma unroll
  for (int m = 0; m < 8; m++) aofs[m] = wr*8192 + m*1024 + aswz;
  #pragma unroll
  for (int n = 0; n < 4; n++) bofs[n] = wc*4096 + n*1024 + aswz;

  // staging: linear LDS dest, inverse-permuted global source (R6-verified)
  int s8  = (tid & 7) ^ ((tid >> 3) & 7);
  int rl  = wv*16 + (((tid >> 3) & 7) << 1) + (s8 >> 2);
  int kc  = (s8 & 3) << 4;
  int sA0 = (brow + rl)*(HD*2) + kc;
  int sA1 = sA0 + 128*(HD*2);
  int sB0 = (bcol + rl)*(HD*2) + kc;
  int sB1 = sB0 + 128*(HD*2);
  int ldst0 = (wv << 10);          // wave-uniform LDS dest (+lane*16 by HW)
  int ldst1 = (wv << 10) + 8192;

  const char* Xb = (const char*)Xh;
  const char* Wb = (const char*)Wh;

  float4v acc[8][4];
  #pragma unroll
  for (int m=0;m<8;m++)
    #pragma unroll
    for (int n=0;n<4;n++) acc[m][n] = (float4v){0.f,0.f,0.f,0.f};

  // prologue: tile0 u0..u3 + tile1 u0,u1 (12 loads); vmcnt(4) -> tile0 landed
  gload_lds16(Xb + sA0,       ldsby + 0     + ldst0);
  gload_lds16(Xb + sA1,       ldsby + 0     + ldst1);
  gload_lds16(Wb + sB0,       ldsby + 16384 + ldst0);
  gload_lds16(Wb + sB1,       ldsby + 16384 + ldst1);
  gload_lds16(Xb + (sA0+64),  ldsby + 32768 + ldst0);
  gload_lds16(Xb + (sA1+64),  ldsby + 32768 + ldst1);
  gload_lds16(Wb + (sB0+64),  ldsby + 49152 + ldst0);
  gload_lds16(Wb + (sB1+64),  ldsby + 49152 + ldst1);
  gload_lds16(Xb + (sA0+128), ldsby + 65536 + ldst0);
  gload_lds16(Xb + (sA1+128), ldsby + 65536 + ldst1);
  gload_lds16(Wb + (sB0+128), ldsby + 81920 + ldst0);
  gload_lds16(Wb + (sB1+128), ldsby + 81920 + ldst1);
  asm volatile("s_waitcnt vmcnt(4)" ::: "memory");
  __builtin_amdgcn_s_barrier();

  // pre-read phase A(0) lo set
  half8 pfa[4], pfb[4];
  #pragma unroll
  for (int n=0;n<4;n++) pfb[n] = *(const half8*)(ldsby + 16384 + bofs[n]);
  #pragma unroll
  for (int m=0;m<4;m++) pfa[m] = *(const half8*)(ldsby + aofs[m]);

  int kbn = 128;   // byte k-offset of tile t+1
  #pragma unroll 1
  for (int i = 0; i < 15; ++i) {
    ktile<0,     true,true,true, 4,4>(ldsby, Xb, Wb, sA0,sA1,sB0,sB1, ldst0,ldst1, kbn, aofs, bofs, pfa, pfb, acc);
    kbn += 128;
    ktile<65536, true,true,true, 4,4>(ldsby, Xb, Wb, sA0,sA1,sB0,sB1, ldst0,ldst1, kbn, aofs, bofs, pfa, pfb, acc);
    kbn += 128;
  }
  // t=30: stage tile31 kk1 only; endB drains so tile31 kk1 visible for A(31)
  ktile<0,     true,false,true, 4,0>(ldsby, Xb, Wb, sA0,sA1,sB0,sB1, ldst0,ldst1, kbn, aofs, bofs, pfa, pfb, acc);
  kbn += 128;
  // t=31: no staging, no prefetch
  ktile<65536, false,false,false, -1,-1>(ldsby, Xb, Wb, sA0,sA1,sB0,sB1, ldst0,ldst1, kbn, aofs, bofs, pfa, pfb, acc);

  // ---------------- epilogue: bias + per-row max/sumexp ----------------
  float bv[4];
  #pragma unroll
  for (int n=0;n<4;n++) bv[n] = bias[bcol + wc*64 + n*16 + l15];

  float lsum = 0.f;
  int ch = colt*4 + wc;
  #pragma unroll
  for (int m=0;m<8;m++) {
    #pragma unroll
    for (int r=0;r<4;r++) {
      float v0 = acc[m][0][r] + bv[0];
      float v1 = acc[m][1][r] + bv[1];
      float v2 = acc[m][2][r] + bv[2];
      float v3 = acc[m][3][r] + bv[3];
      if (computeSum) lsum += v0+v1+v2+v3;
      float mx = fmaxf(fmaxf(v0,v1), fmaxf(v2,v3));
      #pragma unroll
      for (int off=1; off<16; off<<=1) mx = fmaxf(mx, __shfl_xor(mx, off, 64));
      float se = __expf(v0-mx)+__expf(v1-mx)+__expf(v2-mx)+__expf(v3-mx);
      #pragma unroll
      for (int off=1; off<16; off<<=1) se += __shfl_xor(se, off, 64);
      if (l15 == 0) {
        int row = brow + wr*128 + m*16 + (lane>>4)*4 + r;
        pmax[(size_t)row*NCH + ch] = mx;
        psum[(size_t)row*NCH + ch] = se;
      }
    }
  }

  if (computeSum) {
    #pragma unroll
    for (int off=1; off<64; off<<=1) lsum += __shfl_xor(lsum, off, 64);
    __syncthreads();
    float* red = (float*)ldsbuf;
    if (lane == 0) red[wv] = lsum;
    __syncthreads();
    if (tid == 0) {
      float s = 0.f;
      for (int w=0; w<8; w++) s += red[w];
      bsum[blockIdx.x] = s;
    }
  }
}

// ---------- per-row combine ----------
__global__ void row_combine(const float* __restrict__ pmax,
                            const float* __restrict__ psum,
                            const float* __restrict__ mask,
                            float* __restrict__ tok)
{
  int row = blockIdx.x;
  int lane = threadIdx.x;
  float M = -INFINITY;
  for (int c = lane; c < NCH; c += 64) M = fmaxf(M, pmax[(size_t)row*NCH + c]);
  #pragma unroll
  for (int off=1; off<64; off<<=1) M = fmaxf(M, __shfl_xor(M, off, 64));
  float L = 0.f;
  for (int c = lane; c < NCH; c += 64)
    L += psum[(size_t)row*NCH + c] * __expf(pmax[(size_t)row*NCH + c] - M);
  #pragma unroll
  for (int off=1; off<64; off<<=1) L += __shfl_xor(L, off, 64);
  if (lane == 0) tok[row] = -logf(L) * mask[row];
}

// ---------- finalize ----------
__global__ void finalize(const float* __restrict__ tokP,
                         const float* __restrict__ tokR,
                         const float* __restrict__ rewards,
                         const float* __restrict__ bsum, int nbsum,
                         float* __restrict__ out)
{
  __shared__ float red[256];
  __shared__ float seqP[4], seqR[4];
  int t = threadIdx.x;
  for (int b=0; b<4; b++) {
    float v = tokP[b*512 + t] + tokP[b*512 + 256 + t];
    red[t] = v; __syncthreads();
    for (int s=128; s>0; s>>=1) { if (t < s) red[t] += red[t+s]; __syncthreads(); }
    if (t == 0) seqP[b] = red[0];
    __syncthreads();
    v = tokR[b*512 + t] + tokR[b*512 + 256 + t];
    red[t] = v; __syncthreads();
    for (int s=128; s>0; s>>=1) { if (t < s) red[t] += red[t+s]; __syncthreads(); }
    if (t == 0) seqR[b] = red[0];
    __syncthreads();
  }
  float ls = 0.f;
  for (int i=t; i<nbsum; i+=256) ls += bsum[i];
  red[t] = ls; __syncthreads();
  for (int s=128; s>0; s>>=1) { if (t < s) red[t] += red[t+s]; __syncthreads(); }
  if (t == 0) {
    float r0=rewards[0], r1=rewards[1], r2=rewards[2], r3=rewards[3];
    float rm = (r0+r1+r2+r3)*0.25f;
    float var = ((r0-rm)*(r0-rm)+(r1-rm)*(r1-rm)+(r2-rm)*(r2-rm)+(r3-rm)*(r3-rm))/3.f;
    float rstd = sqrtf(var);
    float adv[4] = {r0-rm, r1-rm, r2-rm, r3-rm};
    if (rstd > 0.f) { for (int b=0;b<4;b++) adv[b] /= rstd; }
    float loss=0.f, sm=0.f, km=0.f;
    for (int b=0;b<4;b++) {
      float kl = seqP[b] - seqR[b];
      loss += -(adv[b]*seqP[b]) + 0.1f*kl;
      sm += seqP[b]; km += kl;
    }
    loss *= 0.25f; sm *= 0.25f; km *= 0.25f;
    float sv = 0.f;
    for (int b=0;b<4;b++) { float d = seqP[b]-sm; sv += d*d; }
    float sstd = sqrtf(sv/3.f);
    out[0] = loss;
    out[1] = sm;
    out[2] = sstd;
    out[3] = red[0] / ((float)TOK * (float)VOC);
    out[4] = km;
  }
}

extern "C" void kernel_launch(void* const* d_in, const int* in_sizes, int n_in,
                              void* d_out, int out_size, void* d_ws, size_t ws_size,
                              hipStream_t stream) {
  const float* W    = (const float*)d_in[0];
  const float* X    = (const float*)d_in[1];
  const float* mask = (const float*)d_in[2];
  const float* rew  = (const float*)d_in[3];
  const float* bias = (const float*)d_in[4];
  const float* Xr   = (const float*)d_in[5];
  const float* Wr   = (const float*)d_in[6];
  const float* br   = (const float*)d_in[7];
  float* out = (float*)d_out;

  float* pmax = (float*)d_ws;                       // 2048*500
  float* psum = pmax + (size_t)TOK*NCH;             // 2048*500
  float* tokP = psum + (size_t)TOK*NCH;             // 2048
  float* tokR = tokP + TOK;                         // 2048
  float* bsum = tokR + TOK;                         // 4096 (pad)

  size_t headFloats = (size_t)TOK*NCH*2 + TOK*2 + 4096;
  size_t offXh = headFloats * 4;
  _Float16* Xh = (_Float16*)((unsigned char*)d_ws + offXh);
  _Float16* Wh = (_Float16*)((unsigned char*)d_ws + offXh + (size_t)TOK*HD*2);

  cvt_f32_f16<<<2048, 256, 0, stream>>>(X,  Xh, TOK*HD/8);
  cvt_f32_f16<<<2048, 256, 0, stream>>>(W,  Wh, VOC*HD/8);
  gemm_stats_f16<<<NBLK, 512, 0, stream>>>(Xh, Wh, bias, pmax, psum, bsum, 1);
  row_combine<<<TOK, 64, 0, stream>>>(pmax, psum, mask, tokP);
  cvt_f32_f16<<<2048, 256, 0, stream>>>(Xr, Xh, TOK*HD/8);
  cvt_f32_f16<<<2048, 256, 0, stream>>>(Wr, Wh, VOC*HD/8);
  gemm_stats_f16<<<NBLK, 512, 0, stream>>>(Xh, Wh, br, pmax, psum, bsum, 0);
  row_combine<<<TOK, 64, 0, stream>>>(pmax, psum, mask, tokR);
  finalize<<<1, 256, 0, stream>>>(tokP, tokR, rew, bsum, NBLK, out);
}